// Round 1
// baseline (65.163 us; speedup 1.0000x reference)
//
#include <hip/hip_runtime.h>
#include <math.h>

#define H_IMG 256
#define W_IMG 512
#define PSZ   224
#define FS    14
#define L     196   // FS*FS
#define DM    384
#define HID   96    // DM/4

// ---- shared helper: replicate reference x_start / y_start computation ----
__device__ __forceinline__ void get_starts(const float* __restrict__ pos, int b,
                                           int& xs, int& ys) {
    float px = pos[b * 2 + 0];
    float py = pos[b * 2 + 1];
    px = fminf(fmaxf(px, 0.0f), 1.0f);
    py = fminf(fmaxf(py, 0.0f), 1.0f);
    // x_start = int(trunc(px*512 - 112)) % 512  (numpy mod -> non-negative)
    int xv = (int)truncf(px * (float)W_IMG - 112.0f);
    xs = ((xv % W_IMG) + W_IMG) % W_IMG;
    // y_start = int(floor(clip(py*256 - 112, 0, 32)))
    float yv = py * (float)H_IMG - 112.0f;
    yv = fminf(fmaxf(yv, 0.0f), (float)(H_IMG - PSZ));
    ys = (int)floorf(yv);
}

// ---- K1: 16x16 average pool of the wraparound crop -> pooled (B,3,196) ----
// grid = B*14 blocks (b, pooled-row i), 256 threads (224 active, one per patch col)
__global__ __launch_bounds__(256) void pool_kernel(const float* __restrict__ img,
                                                   const float* __restrict__ pos,
                                                   float* __restrict__ pooled,
                                                   int B) {
    int blk = blockIdx.x;
    int b = blk / FS;
    int i = blk % FS;
    int t = threadIdx.x;
    int xs, ys;
    get_starts(pos, b, xs, ys);
    if (t < PSZ) {
        int col = xs + t;
        if (col >= W_IMG) col -= W_IMG;   // wraparound
        int row0 = ys + i * 16;
        #pragma unroll
        for (int c = 0; c < 3; ++c) {
            const float* ip = img + ((size_t)(b * 3 + c) * H_IMG) * W_IMG;
            float acc = 0.0f;
            #pragma unroll
            for (int dy = 0; dy < 16; ++dy)
                acc += ip[(size_t)(row0 + dy) * W_IMG + col];
            // sum across the 16 lanes of this column group (groups are wave-aligned)
            acc += __shfl_xor(acc, 1);
            acc += __shfl_xor(acc, 2);
            acc += __shfl_xor(acc, 4);
            acc += __shfl_xor(acc, 8);
            if ((t & 15) == 0)
                pooled[(size_t)(b * 3 + c) * L + i * FS + (t >> 4)] = acc * (1.0f / 256.0f);
        }
    }
}

// ---- K2: A[c][k] = Wp[c,:] @ w1[:,k]; B0[k] = bp @ w1[:,k] + b1[k] ----
__global__ void precompute_kernel(const float* __restrict__ Wp, const float* __restrict__ bp,
                                  const float* __restrict__ w1, const float* __restrict__ b1,
                                  float* __restrict__ A, float* __restrict__ B0) {
    int k = threadIdx.x;
    if (k < HID) {
        float a0 = 0.f, a1 = 0.f, a2 = 0.f, ab = 0.f;
        for (int d = 0; d < DM; ++d) {
            float w = w1[d * HID + k];
            a0 += Wp[0 * DM + d] * w;
            a1 += Wp[1 * DM + d] * w;
            a2 += Wp[2 * DM + d] * w;
            ab += bp[d] * w;
        }
        A[0 * HID + k] = a0;
        A[1 * HID + k] = a1;
        A[2 * HID + k] = a2;
        B0[k] = ab + b1[k];
    }
}

// ---- K3: per token: fusion weight fw + bilinear scalar combos ps/wsum ----
__global__ __launch_bounds__(256) void fw_kernel(const float* __restrict__ pos,
                                                 const float* __restrict__ pooled,
                                                 const float* __restrict__ A,
                                                 const float* __restrict__ B0,
                                                 const float* __restrict__ w2,
                                                 const float* __restrict__ b2,
                                                 float4* __restrict__ metaA,
                                                 float* __restrict__ metaB,
                                                 int B) {
    __shared__ float sA[3 * HID];
    __shared__ float sB0[HID];
    __shared__ float sw2[HID];
    for (int k = threadIdx.x; k < 3 * HID; k += blockDim.x) sA[k] = A[k];
    for (int k = threadIdx.x; k < HID; k += blockDim.x) { sB0[k] = B0[k]; sw2[k] = w2[k]; }
    __syncthreads();

    int idx = blockIdx.x * blockDim.x + threadIdx.x;
    if (idx >= B * L) return;
    int b = idx / L;
    int l = idx % L;
    int i = l / FS;
    int j = l % FS;

    const float* pb = pooled + (size_t)b * 3 * L;
    float p0 = pb[l], p1 = pb[L + l], p2 = pb[2 * L + l];

    // fusion weight: sigmoid( gelu_tanh(B0 + p·A) @ w2 + b2 )
    float s = 0.0f;
    for (int k = 0; k < HID; ++k) {
        float x = sB0[k] + p0 * sA[k] + p1 * sA[HID + k] + p2 * sA[2 * HID + k];
        float inner = 0.7978845608028654f * (x + 0.044715f * x * x * x);
        float g = 0.5f * x * (1.0f + tanhf(inner));
        s += g * sw2[k];
    }
    float fw = 1.0f / (1.0f + expf(-(s + b2[0])));

    // bilinear sample coordinates on the 14x14 local map (replicate ref math)
    int xs, ys;
    get_starts(pos, b, xs, ys);
    float uj = ((j + 0.5f) * 2.0f) / 14.0f - 1.0f;
    float ui = ((i + 0.5f) * 2.0f) / 14.0f - 1.0f;
    float gx = (224.0f / 512.0f) * uj + ((2.0f * (float)xs + 224.0f) / 512.0f - 1.0f);
    float gy = (224.0f / 256.0f) * ui + ((2.0f * (float)ys + 224.0f) / 256.0f - 1.0f);
    float ix = (gx + 1.0f) * 7.0f - 0.5f;   // (gx+1)*(W*0.5)-0.5, W=14
    float iy = (gy + 1.0f) * 7.0f - 0.5f;
    float x0f = floorf(ix), y0f = floorf(iy);
    float wx1 = ix - x0f, wx0 = 1.0f - wx1;
    float wy1 = iy - y0f, wy0 = 1.0f - wy1;
    int x0 = (int)x0f, y0 = (int)y0f;
    int x1 = x0 + 1, y1 = y0 + 1;

    float ps0 = 0.f, ps1 = 0.f, ps2 = 0.f, wsum = 0.f;
    const int   cx[4] = { x0, x1, x0, x1 };
    const int   cy[4] = { y0, y0, y1, y1 };
    const float cw[4] = { wy0 * wx0, wy0 * wx1, wy1 * wx0, wy1 * wx1 };
    #pragma unroll
    for (int n = 0; n < 4; ++n) {
        int X = cx[n], Y = cy[n];
        if (X >= 0 && X < FS && Y >= 0 && Y < FS) {
            float w = cw[n];
            int li = Y * FS + X;
            ps0 += w * pb[li];
            ps1 += w * pb[L + li];
            ps2 += w * pb[2 * L + li];
            wsum += w;
        }
    }
    metaA[idx] = make_float4(fw, wsum, ps0, ps1);
    metaB[idx] = ps2;
}

// ---- K4: out = global + fw*(wsum*bp + ps0*Wp0 + ps1*Wp1 + ps2*Wp2), float4 ----
__global__ __launch_bounds__(256) void update_kernel(const float* __restrict__ gf,
                                                     const float* __restrict__ Wp,
                                                     const float* __restrict__ bp,
                                                     const float4* __restrict__ metaA,
                                                     const float* __restrict__ metaB,
                                                     float* __restrict__ out,
                                                     int total4) {
    int idx4 = blockIdx.x * blockDim.x + threadIdx.x;
    if (idx4 >= total4) return;
    int token = idx4 / (DM / 4);
    int d4 = idx4 % (DM / 4);

    float4 m = metaA[token];
    float ps2 = metaB[token];
    float fw = m.x, wsum = m.y, ps0 = m.z, ps1 = m.w;

    const float4* gf4 = (const float4*)gf;
    const float4* Wp4 = (const float4*)Wp;
    const float4* bp4 = (const float4*)bp;
    float4 g  = gf4[idx4];
    float4 w0 = Wp4[0 * (DM / 4) + d4];
    float4 w1v = Wp4[1 * (DM / 4) + d4];
    float4 w2v = Wp4[2 * (DM / 4) + d4];
    float4 bv = bp4[d4];

    float4 o;
    o.x = g.x + fw * (wsum * bv.x + ps0 * w0.x + ps1 * w1v.x + ps2 * w2v.x);
    o.y = g.y + fw * (wsum * bv.y + ps0 * w0.y + ps1 * w1v.y + ps2 * w2v.y);
    o.z = g.z + fw * (wsum * bv.z + ps0 * w0.z + ps1 * w1v.z + ps2 * w2v.z);
    o.w = g.w + fw * (wsum * bv.w + ps0 * w0.w + ps1 * w1v.w + ps2 * w2v.w);
    ((float4*)out)[idx4] = o;
}

extern "C" void kernel_launch(void* const* d_in, const int* in_sizes, int n_in,
                              void* d_out, int out_size, void* d_ws, size_t ws_size,
                              hipStream_t stream) {
    const float* images    = (const float*)d_in[0];
    const float* positions = (const float*)d_in[1];
    const float* gf        = (const float*)d_in[2];
    const float* Wp        = (const float*)d_in[3];
    const float* bp        = (const float*)d_in[4];
    const float* w1        = (const float*)d_in[5];
    const float* b1        = (const float*)d_in[6];
    const float* w2        = (const float*)d_in[7];
    const float* b2        = (const float*)d_in[8];

    const int B = in_sizes[1] / 2;   // positions is (B,2)

    // workspace layout (floats)
    float* ws = (float*)d_ws;
    float*  pooled = ws;                                  // B*3*196
    float*  A      = ws + (size_t)B * 3 * L;              // 288
    float*  B0     = A + 3 * HID;                         // 96
    float*  metaAf = B0 + HID;                            // B*196 float4
    float4* metaA  = (float4*)metaAf;
    float*  metaB  = metaAf + (size_t)B * L * 4;          // B*196

    // K1: pooling
    hipLaunchKernelGGL(pool_kernel, dim3(B * FS), dim3(256), 0, stream,
                       images, positions, pooled, B);
    // K2: tiny precompute
    hipLaunchKernelGGL(precompute_kernel, dim3(1), dim3(128), 0, stream,
                       Wp, bp, w1, b1, A, B0);
    // K3: per-token fw + bilinear combos
    int tok = B * L;
    hipLaunchKernelGGL(fw_kernel, dim3((tok + 255) / 256), dim3(256), 0, stream,
                       positions, pooled, A, B0, w2, b2, metaA, metaB, B);
    // K4: fused elementwise update
    int total4 = tok * (DM / 4);
    hipLaunchKernelGGL(update_kernel, dim3((total4 + 255) / 256), dim3(256), 0, stream,
                       gf, Wp, bp, metaA, metaB, (float*)d_out, total4);
}

// Round 2
// 59.908 us; speedup vs baseline: 1.0877x; 1.0877x over previous
//
#include <hip/hip_runtime.h>
#include <math.h>

#define H_IMG 256
#define W_IMG 512
#define PSZ   224
#define FS    14
#define L     196   // FS*FS
#define DM    384
#define HID   96    // DM/4
#define TPB   32    // tokens per block in fused kernel

// ---- replicate reference x_start / y_start computation ----
__device__ __forceinline__ void get_starts(const float* __restrict__ pos, int b,
                                           int& xs, int& ys) {
    float px = pos[b * 2 + 0];
    float py = pos[b * 2 + 1];
    px = fminf(fmaxf(px, 0.0f), 1.0f);
    py = fminf(fmaxf(py, 0.0f), 1.0f);
    int xv = (int)truncf(px * (float)W_IMG - 112.0f);
    xs = ((xv % W_IMG) + W_IMG) % W_IMG;
    float yv = py * (float)H_IMG - 112.0f;
    yv = fminf(fmaxf(yv, 0.0f), (float)(H_IMG - PSZ));
    ys = (int)floorf(yv);
}

// ---- K1: 16x16 avg-pool of wraparound crop -> pooled (B,3,196)
//      block 0 additionally computes A = Wp@w1 (3x96), B0 = bp@w1 + b1 ----
// grid = B*14 blocks (b, pooled-row i), 256 threads (224 active)
__global__ __launch_bounds__(256) void pool_pre_kernel(
    const float* __restrict__ img, const float* __restrict__ pos,
    const float* __restrict__ Wp,  const float* __restrict__ bp,
    const float* __restrict__ w1,  const float* __restrict__ b1,
    float* __restrict__ pooled, float* __restrict__ A, float* __restrict__ B0,
    int B)
{
    const int HW = H_IMG * W_IMG;
    int blk = blockIdx.x;
    int b = blk / FS;
    int i = blk % FS;
    int t = threadIdx.x;
    int xs, ys;
    get_starts(pos, b, xs, ys);

    if (t < PSZ) {
        int col = xs + t;
        if (col >= W_IMG) col -= W_IMG;   // wraparound
        int row0 = ys + i * 16;
        const float* ip = img + (size_t)b * 3 * HW + (size_t)row0 * W_IMG + col;
        float a0 = 0.f, a1 = 0.f, a2 = 0.f;
        #pragma unroll
        for (int dy = 0; dy < 16; ++dy) {
            const float* r = ip + dy * W_IMG;
            a0 += r[0];           // 48 independent loads in flight
            a1 += r[HW];
            a2 += r[2 * HW];
        }
        // sum the 16 lanes of each column group (groups are wave-aligned)
        #pragma unroll
        for (int d = 1; d < 16; d <<= 1) {
            a0 += __shfl_xor(a0, d);
            a1 += __shfl_xor(a1, d);
            a2 += __shfl_xor(a2, d);
        }
        if ((t & 15) == 0) {
            int li = i * FS + (t >> 4);
            pooled[((size_t)b * 3 + 0) * L + li] = a0 * (1.0f / 256.0f);
            pooled[((size_t)b * 3 + 1) * L + li] = a1 * (1.0f / 256.0f);
            pooled[((size_t)b * 3 + 2) * L + li] = a2 * (1.0f / 256.0f);
        }
    }

    // side job: tiny precompute, hidden under the pool kernel's runtime
    if (blk == 0 && t < HID) {
        float a0 = 0.f, a1 = 0.f, a2 = 0.f, ab = 0.f;
        #pragma unroll 4
        for (int d = 0; d < DM; ++d) {
            float w = w1[d * HID + t];
            a0 += Wp[0 * DM + d] * w;
            a1 += Wp[1 * DM + d] * w;
            a2 += Wp[2 * DM + d] * w;
            ab += bp[d] * w;
        }
        A[0 * HID + t] = a0;
        A[1 * HID + t] = a1;
        A[2 * HID + t] = a2;
        B0[t] = ab + b1[t];
    }
}

// ---- K2 (fused): per-token fusion weight + bilinear combos + gated update ----
// grid = ceil(B*L / 32) blocks, 256 threads. Phase 1: 8 lanes/token compute fw.
// Phase 2: stream out = gf + fw*(wsum*bp + ps0*Wp0 + ps1*Wp1 + ps2*Wp2) as float4.
__global__ __launch_bounds__(256) void fused_update_kernel(
    const float* __restrict__ pos, const float* __restrict__ pooled,
    const float* __restrict__ A,   const float* __restrict__ B0,
    const float* __restrict__ w2,  const float* __restrict__ b2,
    const float* __restrict__ gf,  const float* __restrict__ Wp,
    const float* __restrict__ bp,  float* __restrict__ out, int B)
{
    __shared__ float  sA[3 * HID];
    __shared__ float  sB0[HID];
    __shared__ float  sw2[HID];
    __shared__ float4 sWp4[3 * DM / 4];   // 288
    __shared__ float4 sbp4[DM / 4];       // 96
    __shared__ float  sMeta[TPB][5];      // fw, wsum, ps0, ps1, ps2

    int tid = threadIdx.x;
    if (tid < 3 * HID) sA[tid] = A[tid];
    if (tid < HID) { sB0[tid] = B0[tid]; sw2[tid] = w2[tid]; }
    { // Wp: 288 float4; bp: 96 float4
        if (tid < 288) sWp4[tid] = ((const float4*)Wp)[tid];
        if (tid < 96)  sbp4[tid] = ((const float4*)bp)[tid];
    }
    __syncthreads();

    const int nTok = B * L;
    int bt = blockIdx.x * TPB;
    int g = tid >> 3;           // local token 0..31
    int s = tid & 7;            // lane within token group
    int token = bt + g;
    if (token >= nTok) token = nTok - 1;   // safe clamp (exact for B=128)
    int b = token / L;
    int l = token % L;

    const float* pb = pooled + (size_t)b * 3 * L;
    float p0 = pb[l], p1 = pb[L + l], p2 = pb[2 * L + l];

    float acc = 0.0f;
    #pragma unroll
    for (int m = 0; m < 12; ++m) {
        int k = s + 8 * m;
        float x = sB0[k] + p0 * sA[k] + p1 * sA[HID + k] + p2 * sA[2 * HID + k];
        // gelu tanh-approx with exp-based tanh (saturates cleanly, no NaN)
        float e = __expf(1.5957691216057308f * (x + 0.044715f * x * x * x)); // 2*sqrt(2/pi)
        float th = 1.0f - 2.0f / (e + 1.0f);
        acc += 0.5f * x * (1.0f + th) * sw2[k];
    }
    acc += __shfl_xor(acc, 1);
    acc += __shfl_xor(acc, 2);
    acc += __shfl_xor(acc, 4);

    if (s == 0) {
        float fw = 1.0f / (1.0f + __expf(-(acc + b2[0])));

        int xs, ys;
        get_starts(pos, b, xs, ys);
        int i = l / FS, j = l % FS;
        float uj = ((j + 0.5f) * 2.0f) / 14.0f - 1.0f;
        float ui = ((i + 0.5f) * 2.0f) / 14.0f - 1.0f;
        float gx = (224.0f / 512.0f) * uj + ((2.0f * (float)xs + 224.0f) / 512.0f - 1.0f);
        float gy = (224.0f / 256.0f) * ui + ((2.0f * (float)ys + 224.0f) / 256.0f - 1.0f);
        float ix = (gx + 1.0f) * 7.0f - 0.5f;
        float iy = (gy + 1.0f) * 7.0f - 0.5f;
        float x0f = floorf(ix), y0f = floorf(iy);
        float wx1 = ix - x0f, wx0 = 1.0f - wx1;
        float wy1 = iy - y0f, wy0 = 1.0f - wy1;
        int x0 = (int)x0f, y0 = (int)y0f;
        int x1 = x0 + 1, y1 = y0 + 1;

        float ps0 = 0.f, ps1 = 0.f, ps2 = 0.f, wsum = 0.f;
        const int   cx[4] = { x0, x1, x0, x1 };
        const int   cy[4] = { y0, y0, y1, y1 };
        const float cw[4] = { wy0 * wx0, wy0 * wx1, wy1 * wx0, wy1 * wx1 };
        #pragma unroll
        for (int n = 0; n < 4; ++n) {
            int X = cx[n], Y = cy[n];
            if (X >= 0 && X < FS && Y >= 0 && Y < FS) {
                float w = cw[n];
                int li = Y * FS + X;
                ps0 += w * pb[li];
                ps1 += w * pb[L + li];
                ps2 += w * pb[2 * L + li];
                wsum += w;
            }
        }
        sMeta[g][0] = fw;  sMeta[g][1] = wsum;
        sMeta[g][2] = ps0; sMeta[g][3] = ps1; sMeta[g][4] = ps2;
    }
    __syncthreads();

    // phase 2: 32 tokens * 96 float4 = 3072 items = 12 iterations of 256
    const float4* gf4  = (const float4*)gf  + (size_t)bt * (DM / 4);
    float4*       out4 = (float4*)out       + (size_t)bt * (DM / 4);
    long long maxItem = (long long)(nTok - bt) * (DM / 4);   // tail guard
    #pragma unroll
    for (int it = 0; it < 12; ++it) {
        int item = it * 256 + tid;
        if (item >= maxItem) break;
        int tl = item / (DM / 4);
        int d4 = item - tl * (DM / 4);
        float fw   = sMeta[tl][0];
        float wsum = sMeta[tl][1];
        float ps0  = sMeta[tl][2];
        float ps1  = sMeta[tl][3];
        float ps2  = sMeta[tl][4];
        float4 g4 = gf4[item];
        float4 w0 = sWp4[d4];
        float4 w1v = sWp4[96 + d4];
        float4 w2v = sWp4[192 + d4];
        float4 bv = sbp4[d4];
        float4 o;
        o.x = g4.x + fw * (wsum * bv.x + ps0 * w0.x + ps1 * w1v.x + ps2 * w2v.x);
        o.y = g4.y + fw * (wsum * bv.y + ps0 * w0.y + ps1 * w1v.y + ps2 * w2v.y);
        o.z = g4.z + fw * (wsum * bv.z + ps0 * w0.z + ps1 * w1v.z + ps2 * w2v.z);
        o.w = g4.w + fw * (wsum * bv.w + ps0 * w0.w + ps1 * w1v.w + ps2 * w2v.w);
        out4[item] = o;
    }
}

extern "C" void kernel_launch(void* const* d_in, const int* in_sizes, int n_in,
                              void* d_out, int out_size, void* d_ws, size_t ws_size,
                              hipStream_t stream) {
    const float* images    = (const float*)d_in[0];
    const float* positions = (const float*)d_in[1];
    const float* gf        = (const float*)d_in[2];
    const float* Wp        = (const float*)d_in[3];
    const float* bp        = (const float*)d_in[4];
    const float* w1        = (const float*)d_in[5];
    const float* b1        = (const float*)d_in[6];
    const float* w2        = (const float*)d_in[7];
    const float* b2        = (const float*)d_in[8];

    const int B = in_sizes[1] / 2;   // positions is (B,2)

    float* ws = (float*)d_ws;
    float* pooled = ws;                         // B*3*196
    float* A      = ws + (size_t)B * 3 * L;     // 288
    float* B0     = A + 3 * HID;                // 96

    hipLaunchKernelGGL(pool_pre_kernel, dim3(B * FS), dim3(256), 0, stream,
                       images, positions, Wp, bp, w1, b1, pooled, A, B0, B);

    int nTok = B * L;
    hipLaunchKernelGGL(fused_update_kernel, dim3((nTok + TPB - 1) / TPB), dim3(256), 0, stream,
                       positions, pooled, A, B0, w2, b2, gf, Wp, bp, (float*)d_out, B);
}